// Round 6
// baseline (1247.424 us; speedup 1.0000x reference)
//
#include <hip/hip_runtime.h>
#include <hip/hip_cooperative_groups.h>
#include <float.h>

namespace cg = cooperative_groups;

// Problem constants
#define NUM_Q 8
#define BN    8192      // B*N tokens
#define D     512
#define C     1024

// d_out layout (floats): [quantized_out | indices(as float) | losses]
#define QOUT_OFF 0
#define IDX_OFF  (BN * D)
#define LOSS_OFF (IDX_OFF + BN * NUM_Q)

// d_ws byte offsets: R_f16 | cb_f16 (all layers) | top2 | e2
#define RF16_B   0
#define CBF16_B  (BN * D * 2)                          // +8 MB
#define TOP2_B   (CBF16_B + NUM_Q * C * D * 2)         // +8 MB
#define E2_B     (TOP2_B + BN * 16 * 8)                // +1 MB

typedef _Float16 f16x8 __attribute__((ext_vector_type(8)));
typedef float    f32x4 __attribute__((ext_vector_type(4)));

// Approx-GEMM tiling: 128 tokens x 128 codewords, BK=64, 8 waves (64x32 tiles)
#define TM 128
#define TN 128
#define BK 64
#define GRID    256                // 1 block/CU -- cooperative launch always fits
#define THREADS 512
#define GSTRIDE (GRID * THREADS)   // 131072

__device__ __forceinline__ unsigned fkey(float f) {
    unsigned u = __float_as_uint(f);
    return (u & 0x80000000u) ? ~u : (u | 0x80000000u);
}
__device__ __forceinline__ unsigned long long u64min(unsigned long long a, unsigned long long b) {
    return a < b ? a : b;
}
__device__ __forceinline__ unsigned long long u64max(unsigned long long a, unsigned long long b) {
    return a > b ? a : b;
}
__device__ __forceinline__ unsigned long long shfl_xor_u64(unsigned long long v, int m) {
    int lo = __shfl_xor((int)(unsigned)v, m, 64);
    int hi = __shfl_xor((int)(unsigned)(v >> 32), m, 64);
    return ((unsigned long long)(unsigned)hi << 32) | (unsigned)lo;
}
__device__ __forceinline__ void glds16(const void* g, void* l) {
    __builtin_amdgcn_global_load_lds((const __attribute__((address_space(1))) void*)g,
                                     (__attribute__((address_space(3))) void*)l, 16, 0, 0);
}

__global__ __launch_bounds__(THREADS, 2) void rvq_mega_kernel(
    const float* __restrict__ x, const float* __restrict__ cbs,
    float* __restrict__ out, char* __restrict__ ws)
{
    cg::grid_group grid = cg::this_grid();

    __shared__ __align__(16) char AB[32768];   // approx: A|B tiles; rescore: r rows
    __shared__ float lsum[8];

    _Float16* Rf  = (_Float16*)(ws + RF16_B);
    _Float16* cbf = (_Float16*)(ws + CBF16_B);
    unsigned long long* top2 = (unsigned long long*)(ws + TOP2_B);
    float* e2ws = (float*)(ws + E2_B);

    const int tid  = threadIdx.x;
    const int lane = tid & 63;
    const int wv   = tid >> 6;
    const int gtid = blockIdx.x * THREADS + tid;

    // ================= phase 0: init =================
    {
        for (int i = gtid; i < BN * D / 8; i += GSTRIDE) {
            const float* xp = x + (size_t)i * 8;
            float4 a = *(const float4*)xp;
            float4 b = *(const float4*)(xp + 4);
            float* rp = out + QOUT_OFF + (size_t)i * 8;
            *(float4*)rp = a;
            *(float4*)(rp + 4) = b;
            f16x8 h;
            h[0]=(_Float16)a.x; h[1]=(_Float16)a.y; h[2]=(_Float16)a.z; h[3]=(_Float16)a.w;
            h[4]=(_Float16)b.x; h[5]=(_Float16)b.y; h[6]=(_Float16)b.z; h[7]=(_Float16)b.w;
            *(f16x8*)(Rf + (size_t)i * 8) = h;
        }
        const int wid = gtid >> 6;                 // 0..2047
        for (int row = wid; row < NUM_Q * C; row += GSTRIDE / 64) {
            const float* p = cbs + (size_t)row * D + lane * 8;
            float4 a = *(const float4*)p;
            float4 b = *(const float4*)(p + 4);
            f16x8 h;
            h[0]=(_Float16)a.x; h[1]=(_Float16)a.y; h[2]=(_Float16)a.z; h[3]=(_Float16)a.w;
            h[4]=(_Float16)b.x; h[5]=(_Float16)b.y; h[6]=(_Float16)b.z; h[7]=(_Float16)b.w;
            *(f16x8*)(cbf + (size_t)row * D + lane * 8) = h;
            float ss = a.x*a.x + a.y*a.y + a.z*a.z + a.w*a.w
                     + b.x*b.x + b.y*b.y + b.z*b.z + b.w*b.w;
#pragma unroll
            for (int off = 32; off >= 1; off >>= 1) ss += __shfl_xor(ss, off, 64);
            if (lane == 0) e2ws[row] = ss;
        }
        if (gtid < NUM_Q) out[LOSS_OFF + gtid] = 0.0f;
    }
    grid.sync();

    // approx-phase lane constants
    const int wm = wv & 1;
    const int wn = wv >> 1;
    const int lm = lane & 15;
    const int lq = lane >> 4;
    const int m7 = lm & 7;

    for (int q = 0; q < NUM_Q; ++q) {
        const _Float16* cbfq = cbf + (size_t)q * C * D;
        const float*    cbq  = cbs + (size_t)q * C * D;
        const float*    e2   = e2ws + (size_t)q * C;

        // ================= approx phase: 2 tiles per block =================
        for (int tile = 0; tile < 2; ++tile) {
            const int tileId = blockIdx.x + tile * GRID;   // 0..511
            const int mg = tileId & 63;
            const int nb = tileId >> 6;
            const int tok0 = mg * TM;
            const int cb0  = nb * TN;

            const _Float16* gsrc[4];
            char* ldst[4];
#pragma unroll
            for (int j = 0; j < 4; ++j) {
                const int qq = wv * 4 + j;
                const int ps = (qq & 15) * 64 + lane;
                const int r  = ps >> 3;
                const int g  = (ps & 7) ^ (r & 7);
                gsrc[j] = (qq < 16) ? (Rf   + (size_t)(tok0 + r) * D + g * 8)
                                    : (cbfq + (size_t)(cb0  + r) * D + g * 8);
                ldst[j] = AB + qq * 1024;
            }

            f32x4 acc[4][2];
#pragma unroll
            for (int mt = 0; mt < 4; ++mt)
#pragma unroll
                for (int nt = 0; nt < 2; ++nt)
                    acc[mt][nt] = (f32x4){0.f, 0.f, 0.f, 0.f};

            for (int kb = 0; kb < D / BK; ++kb) {
                const int kc = kb * BK;
                __syncthreads();                 // prior LDS consumers done
#pragma unroll
                for (int j = 0; j < 4; ++j)
                    glds16(gsrc[j] + kc, ldst[j]);
                __syncthreads();                 // staging drained

#pragma unroll
                for (int kh = 0; kh < 2; ++kh) {
                    f16x8 ah[4], bh[2];
                    const int xoff = ((kh * 4 + lq) ^ m7) * 16;
#pragma unroll
                    for (int mt = 0; mt < 4; ++mt) {
                        const int rr = wm * 64 + mt * 16 + lm;
                        ah[mt] = *(const f16x8*)(AB + rr * 128 + xoff);
                    }
#pragma unroll
                    for (int nt = 0; nt < 2; ++nt) {
                        const int rr = wn * 32 + nt * 16 + lm;
                        bh[nt] = *(const f16x8*)(AB + 16384 + rr * 128 + xoff);
                    }
#pragma unroll
                    for (int mt = 0; mt < 4; ++mt)
#pragma unroll
                        for (int nt = 0; nt < 2; ++nt)
                            acc[mt][nt] = __builtin_amdgcn_mfma_f32_16x16x32_f16(ah[mt], bh[nt], acc[mt][nt], 0, 0, 0);
                }
            }

            __syncthreads();   // reuse AB as cross-wave top-2 scratch
            unsigned long long (*part)[TM][2] = (unsigned long long (*)[TM][2])AB;

            const int n0 = cb0 + wn * 32 + lm;
            const float e2v0 = e2[n0];
            const float e2v1 = e2[n0 + 16];

#pragma unroll
            for (int mt = 0; mt < 4; ++mt) {
#pragma unroll
                for (int r = 0; r < 4; ++r) {
                    float s0 = e2v0 - 2.0f * acc[mt][0][r];
                    float s1 = e2v1 - 2.0f * acc[mt][1][r];
                    unsigned long long pa = ((unsigned long long)fkey(s0) << 32) | (unsigned)n0;
                    unsigned long long pb = ((unsigned long long)fkey(s1) << 32) | (unsigned)(n0 + 16);
                    unsigned long long lo = u64min(pa, pb);
                    unsigned long long hi = u64max(pa, pb);
#pragma unroll
                    for (int m = 1; m < 16; m <<= 1) {
                        unsigned long long o1 = shfl_xor_u64(lo, m);
                        unsigned long long o2 = shfl_xor_u64(hi, m);
                        unsigned long long n1 = u64min(lo, o1);
                        unsigned long long n2 = u64min(u64max(lo, o1), u64min(hi, o2));
                        lo = n1; hi = n2;
                    }
                    if (lm == 0) {
                        const int trow = wm * 64 + mt * 16 + lq * 4 + r;
                        part[wn][trow][0] = lo;
                        part[wn][trow][1] = hi;
                    }
                }
            }
            __syncthreads();
            if (tid < TM) {
                unsigned long long lo = part[0][tid][0];
                unsigned long long hi = part[0][tid][1];
#pragma unroll
                for (int w = 1; w < 4; ++w) {
                    unsigned long long q1 = part[w][tid][0];
                    unsigned long long q2 = part[w][tid][1];
                    unsigned long long n1 = u64min(lo, q1);
                    unsigned long long n2 = u64min(u64max(lo, q1), u64min(hi, q2));
                    lo = n1; hi = n2;
                }
                unsigned long long* dst = top2 + (size_t)(tok0 + tid) * 16 + nb * 2;
                dst[0] = lo;
                dst[1] = hi;
            }
        }
        grid.sync();

        // ===== rescore + update: 32 tokens/block in two 16-token rounds =====
        {
            float* rsh = (float*)AB;    // [16][512]
            float ssw = 0.0f;
#pragma unroll
            for (int s2 = 0; s2 < 2; ++s2) {
                if (s2) __syncthreads();         // protect rsh reuse
                float4 rA[2], rB[2];
#pragma unroll
                for (int s = 0; s < 2; ++s) {
                    const int t = wv * 2 + s;
                    const int tok = blockIdx.x * 32 + s2 * 16 + t;
                    const float* rrow = out + QOUT_OFF + (size_t)tok * D;
                    rA[s] = *(const float4*)(rrow + lane * 8);
                    rB[s] = *(const float4*)(rrow + lane * 8 + 4);
                    *(float4*)&rsh[t * 512 + lane * 8]     = rA[s];
                    *(float4*)&rsh[t * 512 + lane * 8 + 4] = rB[s];
                }
                __syncthreads();

#pragma unroll
                for (int s = 0; s < 2; ++s) {
                    const int t = wv * 2 + s;
                    const int tok = blockIdx.x * 32 + s2 * 16 + t;
                    const int c = lane & 15;
                    const int g = lane >> 4;
                    const unsigned long long pk = top2[(size_t)tok * 16 + c];
                    const int idx = (int)(unsigned)(pk & 0xFFFFFFFFull);
                    const float* crow = cbq + (size_t)idx * D + g * 128;
                    const float* rp   = &rsh[t * 512 + g * 128];
                    float dot = 0.0f;
#pragma unroll 8
                    for (int i = 0; i < 32; ++i) {
                        float4 cv = *(const float4*)(crow + i * 4);
                        float4 rv = *(const float4*)(rp + i * 4);
                        dot += cv.x*rv.x + cv.y*rv.y + cv.z*rv.z + cv.w*rv.w;
                    }
                    dot += __shfl_xor(dot, 16, 64);
                    dot += __shfl_xor(dot, 32, 64);

                    const float sc = e2[idx] - 2.0f * dot;
                    unsigned long long key = ((unsigned long long)fkey(sc) << 32) | (unsigned)idx;
#pragma unroll
                    for (int m = 1; m < 64; m <<= 1) key = u64min(key, shfl_xor_u64(key, m));
                    const int bi = (int)(unsigned)(key & 0xFFFFFFFFull);

                    const float* brow = cbq + (size_t)bi * D + lane * 8;
                    float4 c0 = *(const float4*)brow;
                    float4 c1 = *(const float4*)(brow + 4);
                    float4 n0 = make_float4(rA[s].x - c0.x, rA[s].y - c0.y, rA[s].z - c0.z, rA[s].w - c0.w);
                    float4 n1 = make_float4(rB[s].x - c1.x, rB[s].y - c1.y, rB[s].z - c1.z, rB[s].w - c1.w);
                    float* wr = out + QOUT_OFF + (size_t)tok * D + lane * 8;
                    *(float4*)wr       = n0;
                    *(float4*)(wr + 4) = n1;
                    f16x8 h;
                    h[0]=(_Float16)n0.x; h[1]=(_Float16)n0.y; h[2]=(_Float16)n0.z; h[3]=(_Float16)n0.w;
                    h[4]=(_Float16)n1.x; h[5]=(_Float16)n1.y; h[6]=(_Float16)n1.z; h[7]=(_Float16)n1.w;
                    *(f16x8*)(Rf + (size_t)tok * D + lane * 8) = h;

                    float ss = n0.x*n0.x + n0.y*n0.y + n0.z*n0.z + n0.w*n0.w
                             + n1.x*n1.x + n1.y*n1.y + n1.z*n1.z + n1.w*n1.w;
#pragma unroll
                    for (int off = 32; off >= 1; off >>= 1) ss += __shfl_xor(ss, off, 64);
                    ssw += ss;

                    if (lane == 0)
                        out[IDX_OFF + (size_t)tok * NUM_Q + q] = (float)bi;
                }
            }
            if (lane == 0) lsum[wv] = ssw;
            __syncthreads();
            if (tid == 0) {
                float tot = 0.0f;
#pragma unroll
                for (int i = 0; i < 8; ++i) tot += lsum[i];
                atomicAdd(out + LOSS_OFF + q, tot);
            }
        }
        grid.sync();
    }

    // ================= finalize =================
    for (int i = gtid; i < BN * D / 4; i += GSTRIDE) {
        float4 xv = ((const float4*)x)[i];
        float4 rv = ((float4*)(out + QOUT_OFF))[i];
        ((float4*)(out + QOUT_OFF))[i] =
            make_float4(xv.x - rv.x, xv.y - rv.y, xv.z - rv.z, xv.w - rv.w);
    }
    if (gtid < NUM_Q) out[LOSS_OFF + gtid] *= (1.0f / (float)(BN * D));
}

extern "C" void kernel_launch(void* const* d_in, const int* in_sizes, int n_in,
                              void* d_out, int out_size, void* d_ws, size_t ws_size,
                              hipStream_t stream) {
    const float* x   = (const float*)d_in[0];
    const float* cbs = (const float*)d_in[1];
    float* out = (float*)d_out;
    char* ws = (char*)d_ws;

    void* args[] = { (void*)&x, (void*)&cbs, (void*)&out, (void*)&ws };
    hipLaunchCooperativeKernel((const void*)rvq_mega_kernel,
                               dim3(GRID), dim3(THREADS), args, 0, stream);
}

// Round 7
// 674.919 us; speedup vs baseline: 1.8483x; 1.8483x over previous
//
#include <hip/hip_runtime.h>
#include <float.h>

// Problem constants
#define NUM_Q 8
#define BN    8192      // B*N tokens
#define D     512
#define C     1024

// d_out layout (floats): [quantized_out | indices(as float) | losses]
#define QOUT_OFF 0
#define IDX_OFF  (BN * D)
#define LOSS_OFF (IDX_OFF + BN * NUM_Q)

// d_ws byte offsets: cb f16-hi | cb f16-lo | e2
#define CBHI_B 0
#define CBLO_B (NUM_Q * C * D * 2)            // +8 MB
#define E2_B   (2 * NUM_Q * C * D * 2)        // +16 MB

typedef _Float16 f16x8 __attribute__((ext_vector_type(8)));
typedef float    f32x4 __attribute__((ext_vector_type(4)));

// Layer kernel geometry: 32 tokens x all 1024 codewords per block
#define TPB     32
#define THREADS 512              // 8 waves; wave = 32 tok x 128 col slice
#define GRID    (BN / TPB)       // 256 blocks = 1/CU (LDS-forced)
#define BK      32
#define NCHUNK  (D / BK)         // 16
#define ALD     520              // padded A row stride (f16) -> 2-way banks max

__device__ __forceinline__ unsigned fkey(float f) {
    unsigned u = __float_as_uint(f);
    return (u & 0x80000000u) ? ~u : (u | 0x80000000u);
}
__device__ __forceinline__ unsigned long long u64min(unsigned long long a, unsigned long long b) {
    return a < b ? a : b;
}
__device__ __forceinline__ unsigned long long shfl_xor_u64(unsigned long long v, int m) {
    int lo = __shfl_xor((int)(unsigned)v, m, 64);
    int hi = __shfl_xor((int)(unsigned)(v >> 32), m, 64);
    return ((unsigned long long)(unsigned)hi << 32) | (unsigned)lo;
}
__device__ __forceinline__ void glds16(const void* g, void* l) {
    __builtin_amdgcn_global_load_lds((const __attribute__((address_space(1))) void*)g,
                                     (__attribute__((address_space(3))) void*)l, 16, 0, 0);
}

// ---------------------------------------------------------------------------
// prep: split codebooks into f16 hi/lo mirrors; e2 row norms; zero losses.
// one wave per codebook row.
// ---------------------------------------------------------------------------
__global__ void rvq_prep_kernel(const float* __restrict__ cbs, char* __restrict__ ws,
                                float* __restrict__ out) {
    const int row = blockIdx.x;          // 0 .. NUM_Q*C-1
    const int lane = threadIdx.x;        // 0..63
    _Float16* cbhi = (_Float16*)(ws + CBHI_B);
    _Float16* cblo = (_Float16*)(ws + CBLO_B);
    float* e2ws = (float*)(ws + E2_B);

    const float* p = cbs + (size_t)row * D + lane * 8;
    float4 a = *(const float4*)p;
    float4 b = *(const float4*)(p + 4);
    float v[8] = {a.x, a.y, a.z, a.w, b.x, b.y, b.z, b.w};
    f16x8 h, l;
    float ss = 0.0f;
#pragma unroll
    for (int i = 0; i < 8; ++i) {
        _Float16 hi = (_Float16)v[i];
        h[i] = hi;
        l[i] = (_Float16)(v[i] - (float)hi);
        ss += v[i] * v[i];
    }
    *(f16x8*)(cbhi + (size_t)row * D + lane * 8) = h;
    *(f16x8*)(cblo + (size_t)row * D + lane * 8) = l;
#pragma unroll
    for (int off = 32; off >= 1; off >>= 1) ss += __shfl_xor(ss, off, 64);
    if (lane == 0) e2ws[row] = ss;
    if (row == 0 && lane < NUM_Q) out[LOSS_OFF + lane] = 0.0f;
}

// ---------------------------------------------------------------------------
// one fused layer: exact 3-pass f16 hi/lo MFMA over all C, block-local argmin,
// residual update, loss partial, index write. No inter-block traffic.
// ---------------------------------------------------------------------------
__global__ __launch_bounds__(THREADS, 2) void rvq_layer_kernel(
    const float* __restrict__ Rsrc,      // residual in (x for q==0, else out)
    const _Float16* __restrict__ cbhi,   // layer hi mirror [C][D]
    const _Float16* __restrict__ cblo,   // layer lo mirror [C][D]
    const float* __restrict__ cbf,       // layer fp32 codebook [C][D]
    const float* __restrict__ e2,        // layer e2 [C]
    float* __restrict__ out, int q)
{
    __shared__ __align__(16) _Float16 Ahi[TPB][ALD];   // 33,280 B
    __shared__ __align__(16) _Float16 Alo[TPB][ALD];   // 33,280 B
    __shared__ __align__(16) _Float16 Bsh[C * BK];     // 65,536 B (glds dest)
    __shared__ unsigned long long part[8][TPB];
    __shared__ int   bestIdx[TPB];
    __shared__ float lsum[8];

    const int tid  = threadIdx.x;
    const int lane = tid & 63;
    const int wv   = tid >> 6;
    const int lm   = lane & 15;
    const int lq   = lane >> 4;
    const int tok0 = blockIdx.x * TPB;

    // ---- stage A once: 32 tok x 512 D, f32 -> f16 hi/lo ----
    {
        const int t = tid >> 4;
        const int g = tid & 15;
        const float* rp = Rsrc + (size_t)(tok0 + t) * D + g * 32;
#pragma unroll
        for (int j = 0; j < 4; ++j) {
            float4 v0 = *(const float4*)(rp + j * 8);
            float4 v1 = *(const float4*)(rp + j * 8 + 4);
            float v[8] = {v0.x, v0.y, v0.z, v0.w, v1.x, v1.y, v1.z, v1.w};
            f16x8 h, l;
#pragma unroll
            for (int i = 0; i < 8; ++i) {
                _Float16 hi = (_Float16)v[i];
                h[i] = hi;
                l[i] = (_Float16)(v[i] - (float)hi);
            }
            *(f16x8*)&Ahi[t][g * 32 + j * 8] = h;
            *(f16x8*)&Alo[t][g * 32 + j * 8] = l;
        }
    }

    // glds source indices for this thread's 8 issues per chunk-half:
    // LDS slot s (=issue*64+lane) holds row r=s>>2, octet (s&3)^(r&3).
    int grow[8], goct[8];
#pragma unroll
    for (int j = 0; j < 8; ++j) {
        const int s = (wv * 8 + j) * 64 + lane;
        grow[j] = s >> 2;
        goct[j] = (s & 3) ^ ((s >> 2) & 3);
    }

    f32x4 acc[2][8];
#pragma unroll
    for (int mf = 0; mf < 2; ++mf)
#pragma unroll
        for (int nf = 0; nf < 8; ++nf)
            acc[mf][nf] = (f32x4){0.f, 0.f, 0.f, 0.f};

    for (int kb = 0; kb < NCHUNK; ++kb) {
        const int kc = kb * BK;
        f16x8 ah[2], al[2], bb[8];

        // ---- stage B-hi chunk ----
        __syncthreads();                       // prior Bsh consumers done (also A-writes on kb==0)
#pragma unroll
        for (int j = 0; j < 8; ++j)
            glds16(cbhi + (size_t)grow[j] * D + kc + goct[j] * 8,
                   (char*)Bsh + ((wv * 8 + j) * 64 + lane) * 16);
        __syncthreads();                       // drained

#pragma unroll
        for (int mf = 0; mf < 2; ++mf) {
            ah[mf] = *(const f16x8*)&Ahi[mf * 16 + lm][kc + lq * 8];
            al[mf] = *(const f16x8*)&Alo[mf * 16 + lm][kc + lq * 8];
        }
#pragma unroll
        for (int nf = 0; nf < 8; ++nf) {
            const int col = wv * 128 + nf * 16 + lm;
            bb[nf] = *(const f16x8*)((char*)Bsh + col * 64 + ((lq ^ (col & 3)) << 4));
        }
#pragma unroll
        for (int mf = 0; mf < 2; ++mf)
#pragma unroll
            for (int nf = 0; nf < 8; ++nf) {
                acc[mf][nf] = __builtin_amdgcn_mfma_f32_16x16x32_f16(ah[mf], bb[nf], acc[mf][nf], 0, 0, 0);
                acc[mf][nf] = __builtin_amdgcn_mfma_f32_16x16x32_f16(al[mf], bb[nf], acc[mf][nf], 0, 0, 0);
            }

        // ---- stage B-lo chunk (same buffer) ----
        __syncthreads();
#pragma unroll
        for (int j = 0; j < 8; ++j)
            glds16(cblo + (size_t)grow[j] * D + kc + goct[j] * 8,
                   (char*)Bsh + ((wv * 8 + j) * 64 + lane) * 16);
        __syncthreads();

#pragma unroll
        for (int nf = 0; nf < 8; ++nf) {
            const int col = wv * 128 + nf * 16 + lm;
            bb[nf] = *(const f16x8*)((char*)Bsh + col * 64 + ((lq ^ (col & 3)) << 4));
        }
#pragma unroll
        for (int mf = 0; mf < 2; ++mf)
#pragma unroll
            for (int nf = 0; nf < 8; ++nf)
                acc[mf][nf] = __builtin_amdgcn_mfma_f32_16x16x32_f16(ah[mf], bb[nf], acc[mf][nf], 0, 0, 0);
    }

    // ---- block-local argmin ----
    float e2v[8];
#pragma unroll
    for (int nf = 0; nf < 8; ++nf)
        e2v[nf] = e2[wv * 128 + nf * 16 + lm];

#pragma unroll
    for (int mf = 0; mf < 2; ++mf) {
#pragma unroll
        for (int r = 0; r < 4; ++r) {
            unsigned long long best = ~0ull;
#pragma unroll
            for (int nf = 0; nf < 8; ++nf) {
                const int col = wv * 128 + nf * 16 + lm;
                float s = e2v[nf] - 2.0f * acc[mf][nf][r];
                best = u64min(best, ((unsigned long long)fkey(s) << 32) | (unsigned)col);
            }
#pragma unroll
            for (int m = 1; m < 16; m <<= 1)
                best = u64min(best, shfl_xor_u64(best, m));
            if (lm == 0)
                part[wv][mf * 16 + lq * 4 + r] = best;
        }
    }
    __syncthreads();
    if (tid < TPB) {
        unsigned long long b = part[0][tid];
#pragma unroll
        for (int w = 1; w < 8; ++w) b = u64min(b, part[w][tid]);
        bestIdx[tid] = (int)(unsigned)(b & 0xFFFFFFFFull);
    }
    __syncthreads();

    // ---- fused update: residual -= codeword; loss; index ----
    {
        const int t = tid >> 4;
        const int g = tid & 15;
        const int tok = tok0 + t;
        const int bi = bestIdx[t];
        const float* crow = cbf + (size_t)bi * D + g * 32;
        const float* rp   = Rsrc + (size_t)tok * D + g * 32;
        float* wp         = out + QOUT_OFF + (size_t)tok * D + g * 32;
        float ss = 0.0f;
#pragma unroll
        for (int j = 0; j < 8; ++j) {
            float4 r = *(const float4*)(rp + j * 4);
            float4 c = *(const float4*)(crow + j * 4);
            float4 n = make_float4(r.x - c.x, r.y - c.y, r.z - c.z, r.w - c.w);
            *(float4*)(wp + j * 4) = n;
            ss += n.x * n.x + n.y * n.y + n.z * n.z + n.w * n.w;
        }
        if (g == 0)
            out[IDX_OFF + (size_t)tok * NUM_Q + q] = (float)bi;
#pragma unroll
        for (int off = 32; off >= 1; off >>= 1) ss += __shfl_xor(ss, off, 64);
        if (lane == 0) lsum[wv] = ss;
    }
    __syncthreads();
    if (tid == 0) {
        float tot = 0.0f;
#pragma unroll
        for (int i = 0; i < 8; ++i) tot += lsum[i];
        atomicAdd(out + LOSS_OFF + q, tot);
    }
}

// ---------------------------------------------------------------------------
// finalize: quantized_out = x - residual_final (in place); scale losses
// ---------------------------------------------------------------------------
__global__ void rvq_finalize_kernel(const float* __restrict__ x, float* __restrict__ out) {
    int i = blockIdx.x * blockDim.x + threadIdx.x;
    const float4* x4 = (const float4*)x;
    float4* o4 = (float4*)(out + QOUT_OFF);
    const int n4 = BN * D / 4;
    for (int k = i; k < n4; k += gridDim.x * blockDim.x) {
        float4 xv = x4[k];
        float4 rv = o4[k];
        o4[k] = make_float4(xv.x - rv.x, xv.y - rv.y, xv.z - rv.z, xv.w - rv.w);
    }
    if (i < NUM_Q) out[LOSS_OFF + i] *= (1.0f / (float)(BN * D));
}

extern "C" void kernel_launch(void* const* d_in, const int* in_sizes, int n_in,
                              void* d_out, int out_size, void* d_ws, size_t ws_size,
                              hipStream_t stream) {
    const float* x   = (const float*)d_in[0];
    const float* cbs = (const float*)d_in[1];
    float* out = (float*)d_out;
    char* ws = (char*)d_ws;
    _Float16* cbhi = (_Float16*)(ws + CBHI_B);
    _Float16* cblo = (_Float16*)(ws + CBLO_B);
    float* e2ws = (float*)(ws + E2_B);

    hipLaunchKernelGGL(rvq_prep_kernel, dim3(NUM_Q * C), dim3(64), 0, stream, cbs, ws, out);

    for (int q = 0; q < NUM_Q; ++q) {
        const float* Rsrc = (q == 0) ? x : (out + QOUT_OFF);
        hipLaunchKernelGGL(rvq_layer_kernel, dim3(GRID), dim3(THREADS), 0, stream,
                           Rsrc,
                           cbhi + (size_t)q * C * D,
                           cblo + (size_t)q * C * D,
                           cbs  + (size_t)q * C * D,
                           e2ws + (size_t)q * C,
                           out, q);
    }
    hipLaunchKernelGGL(rvq_finalize_kernel, dim3(1024), dim3(256), 0, stream, x, out);
}